// Round 3
// baseline (1103.130 us; speedup 1.0000x reference)
//
#include <hip/hip_runtime.h>

// HydraBackbonePlus: 10 dilations x {X, diffX} x 32 groups, 9-tap grouped dilated
// conv (8 out-ch per group), per-position argmax/argmin over 8 channels,
// histogram-reduced to (32, 1280, 8) with relu.
//
// R13 vs R12 (421 us, VALUBusy 89% -> LDS pipe co-saturated: 4 SIMDs share 1
// LDS pipe; inner loop = 12 b128 + 16 b32 LDS ops per 8 pos ~= 99% pipe load,
// + 3.8e7 bank-conflict cycles from SR%32==8 read patterns):
//  - Smx commit: unsafeAtomicAdd -> native ds_add_f32 (no-return). 1 LDS op
//    (was ds_read+v_add+ds_write). Single writer/slot, program order kept ->
//    bit-identical. (R11's CAS disaster was the SAFE atomicAdd.)
//  - R>=8 ldsum bank spread: SR = TM+12 (12 mod 32, 16B-aligned) -> 8 s-lanes
//    cover all 32 banks 2-way (free). TM for R=16: 32->16 (NR=2 tiles) so
//    CS stays small: LDS 39424 -> 37568 B, still 4 blocks/CU.
// Kept: 8-wide st-loop, v_max3/v_min3, packed-u64 cmn, per-thread Smx slots.

typedef __fp16 h2_t __attribute__((ext_vector_type(2)));

#define NB    32
#define CIN   12
#define SEQ   8192
#define NG    32
#define CPER  6
#define OUTCH 1280
#define XS_FLOATS 7344   // 12 * 612 = max over DI of CIN*CS (DI=3)
#define GRID  10240      // 20 (di,j) * 32 b * 16 chunks

#define MAX3F(a, b, c) ({ float _r; asm("v_max3_f32 %0, %1, %2, %3" \
    : "=v"(_r) : "v"(a), "v"(b), "v"(c)); _r; })
#define MIN3F(a, b, c) ({ float _r; asm("v_min3_f32 %0, %1, %2, %3" \
    : "=v"(_r) : "v"(a), "v"(b), "v"(c)); _r; })

template <int DI>
__device__ __forceinline__ void hydra_body(
    const float* __restrict__ X, const float* __restrict__ W,
    const int* __restrict__ I, float* __restrict__ out,
    float* Xs, float* Smx, int j, int b, int chunk) {

  constexpr int d   = 1 << DI;
  constexpr int R   = (d < 16) ? d : 16;       // residues per tile row-set
  constexpr int rb  = (DI < 4) ? DI : 4;       // log2(R)
  constexpr int Mm  = SEQ / d;                 // m-extent of a residue
  constexpr int TMc = (R == 16) ? 16 : (512 / R);
  constexpr int TM  = (TMc < Mm) ? TMc : Mm;   // m per tile
  constexpr int MC  = Mm / TM;
  constexpr int RC  = d / R;
  constexpr int NR  = (RC * MC) / 16;          // chunks per block: 1 (DI<4), 2 (DI>=4)
  constexpr int SR  = (R >= 8) ? (TM + 12) : (TM + 8);  // row stride; +12 -> banks
                                               // spread (12 mod 32), 16B aligned
  constexpr int CS  = R * SR + 4;              // channel stride
  constexpr int CL  = (R >= 8) ? TM : (TM * R / 8);  // m per thread per rep
  constexpr int REP = (R == 16) ? 2 : 1;

  const int L = SEQ - j;
  const int tid = threadIdx.x;
  const int g = tid >> 3, s = tid & 7;

  // weights: 8 out-ch x 9 taps -> 4 half2 + 1 f32 tail per channel (40 regs)
  h2_t Wp[8][4];
  float Wt[8];
  {
    const float* wp = W + (size_t)((DI * 2 + j) * 256 + g * 8) * 9;
#pragma unroll
    for (int k = 0; k < 8; ++k) {
#pragma unroll
      for (int t = 0; t < 4; ++t)
        Wp[k][t] = __builtin_amdgcn_cvt_pkrtz(wp[k * 9 + 2 * t], wp[k * 9 + 2 * t + 1]);
      Wt[k] = wp[k * 9 + 8];
    }
  }
  const float* base[CPER];
  {
    const int* ip = I + ((DI * 2 + j) * NG + g) * CPER;
#pragma unroll
    for (int i = 0; i < CPER; ++i) base[i] = Xs + ip[i] * CS;
  }

  // zero the per-thread cmx slots (covered by the staging __syncthreads)
#pragma unroll
  for (int k = 0; k < 8; ++k) Smx[k * 256 + tid] = 0.f;

  // cmn: 8 bins as packed u8 lanes of one u64 (counts <= 64/thread)
  unsigned long long cmnp = 0ull;

  for (int n = 0; n < NR; ++n) {
    const int cidx = chunk + 16 * n;
    const int rc = cidx & (RC - 1);
    const int mc = cidx / RC;
    const int r0 = rc * R;
    const int m0 = mc * TM;

    if (NR > 1 && n) __syncthreads();

    // ---- stage 12-channel tile into LDS, zero-padded; guards hoisted ----
    {
      const float* xb0 = X + (size_t)b * CIN * SEQ;
      if (j == 0) {
        for (int f = tid; f < R * SR; f += 256) {
          int rr = f & (R - 1), mm = f >> rb, mp = m0 + mm - 4;
          int pos = r0 + rr + mp * d;
          bool ok = (mp >= 0) && (pos < L);
          int lo = rr * SR + mm;
          const float* xp = xb0 + pos;
#pragma unroll
          for (int ch = 0; ch < CIN; ++ch) {
            Xs[ch * CS + lo] = ok ? xp[0] : 0.f;
            xp += SEQ;
          }
        }
      } else {
        for (int f = tid; f < R * SR; f += 256) {
          int rr = f & (R - 1), mm = f >> rb, mp = m0 + mm - 4;
          int pos = r0 + rr + mp * d;
          bool ok = (mp >= 0) && (pos < L);
          int lo = rr * SR + mm;
          const float* xp = xb0 + pos;
#pragma unroll
          for (int ch = 0; ch < CIN; ++ch) {
            Xs[ch * CS + lo] = ok ? (xp[1] - xp[0]) : 0.f;
            xp += SEQ;
          }
        }
      }
    }
    __syncthreads();

    // ---- compute: sliding window, dot2 conv, mantissa-tag binning ----
#pragma unroll
    for (int rep = 0; rep < REP; ++rep) {
      int rr = (R == 16) ? (s + (rep << 3)) : (s & (R - 1));
      int mst = (R >= 8) ? 0 : ((s >> rb) * CL);
      int rowoff = rr * SR + mst;

      auto ldsum = [&](int idx) {
        float4 r = *reinterpret_cast<const float4*>(base[0] + idx);
#pragma unroll
        for (int i = 1; i < CPER; ++i) {
          float4 t = *reinterpret_cast<const float4*>(base[i] + idx);
          r.x += t.x; r.y += t.y; r.z += t.z; r.w += t.w;
        }
        return r;
      };

      float4 w0 = ldsum(rowoff);
      float4 w1 = ldsum(rowoff + 4);
#pragma unroll 1
      for (int st = 0; st < CL; st += 8) {
        float4 w2 = ldsum(rowoff + st + 8);
        float4 w3 = ldsum(rowoff + st + 12);
        float xv[16] = {w0.x, w0.y, w0.z, w0.w,
                        w1.x, w1.y, w1.z, w1.w,
                        w2.x, w2.y, w2.z, w2.w,
                        w3.x, w3.y, w3.z, w3.w};
        // even- and odd-aligned f16 pair windows covering xv[0..15]
        h2_t E[8], O[7];
#pragma unroll
        for (int i = 0; i < 8; ++i)
          E[i] = __builtin_amdgcn_cvt_pkrtz(xv[2 * i], xv[2 * i + 1]);
#pragma unroll
        for (int i = 0; i < 7; ++i)
          O[i] = __builtin_amdgcn_cvt_pkrtz(xv[2 * i + 1], xv[2 * i + 2]);
#pragma unroll
        for (int p = 0; p < 8; ++p) {
          const h2_t* P = (p & 1) ? (O + (p >> 1)) : (E + (p >> 1));
          float tail = xv[8 + p];
          // conv + mantissa-tag: zp[k] = (bits(z) & ~7) | k  (v_and_or_b32)
          float zp[8];
#pragma unroll
          for (int k = 0; k < 8; ++k) {
            float acc = Wt[k] * tail;
            acc = __builtin_amdgcn_fdot2(Wp[k][3], P[3], acc, false);
            acc = __builtin_amdgcn_fdot2(Wp[k][2], P[2], acc, false);
            acc = __builtin_amdgcn_fdot2(Wp[k][1], P[1], acc, false);
            acc = __builtin_amdgcn_fdot2(Wp[k][0], P[0], acc, false);
            zp[k] = __uint_as_float((__float_as_uint(acc) & 0xFFFFFFF8u) | (unsigned)k);
          }
          // max/min trees via v_max3/v_min3: 4+4 ops (was 7+7)
          float t1 = MAX3F(zp[0], zp[1], zp[2]);
          float t2 = MAX3F(zp[3], zp[4], zp[5]);
          float t3 = MAX3F(zp[6], zp[7], t1);
          float mxp = fmaxf(t2, t3);
          float u1 = MIN3F(zp[0], zp[1], zp[2]);
          float u2 = MIN3F(zp[3], zp[4], zp[5]);
          float u3 = MIN3F(zp[6], zp[7], u1);
          float mnp = fminf(u2, u3);
          // cmx: per-thread LDS slot, native ds_add_f32 (unsafeAtomicAdd).
          // Single writer per slot, program order -> bit-identical to RMW.
          unsigned mxb = __float_as_uint(mxp);
          unsafeAtomicAdd(&Smx[((mxb & 7u) << 8) + tid], mxp);  // <=8 ulp tag bias
          // cmn: packed-byte histogram in a u64 register
          unsigned mnb = __float_as_uint(mnp);
          cmnp += 1ull << ((mnb & 7u) << 3);
        }
        w0 = w2; w1 = w3;
      }
    }
  }

  __syncthreads();

  // ---- flush ----
  {
    int cbase = (DI * 2 + j) * 64;
    // cmx: thread (g,s) sums bin=s over its 8 member threads
    float sum = 0.f;
#pragma unroll
    for (int s2 = 0; s2 < 8; ++s2) sum += Smx[(s << 8) + (g << 3) + s2];
    atomicAdd(out + ((size_t)b * OUTCH + cbase + g) * 8 + s, sum);

    // cmn: unpack bytes, butterfly over the 8 s-lanes, lane s commits bin s
    int cnts[8];
#pragma unroll
    for (int k = 0; k < 8; ++k) cnts[k] = (int)((cmnp >> (k * 8)) & 0xFFull);
#pragma unroll
    for (int k = 0; k < 8; ++k) {
#pragma unroll
      for (int off = 1; off < 8; off <<= 1)
        cnts[k] += __shfl_xor(cnts[k], off);
    }
    int vn = cnts[0];
#pragma unroll
    for (int k = 1; k < 8; ++k) vn = (s == k) ? cnts[k] : vn;
    atomicAdd(out + ((size_t)b * OUTCH + cbase + 32 + g) * 8 + s, (float)vn);
  }
}

__global__ __launch_bounds__(256, 3) void hydra_fused(
    const float* __restrict__ X, const float* __restrict__ W,
    const int* __restrict__ I, float* __restrict__ out) {
  __shared__ float Xs[XS_FLOATS];
  __shared__ float Smx[2048];   // 8 bins x 256 threads
  int u = blockIdx.x;
  int dj = u % 20;            // consecutive blocks interleave (di,j)
  int rest = u / 20;
  int b = rest & 31;
  int chunk = rest >> 5;
  int j = dj & 1;
  switch (dj >> 1) {
    case 0: hydra_body<0>(X, W, I, out, Xs, Smx, j, b, chunk); break;
    case 1: hydra_body<1>(X, W, I, out, Xs, Smx, j, b, chunk); break;
    case 2: hydra_body<2>(X, W, I, out, Xs, Smx, j, b, chunk); break;
    case 3: hydra_body<3>(X, W, I, out, Xs, Smx, j, b, chunk); break;
    case 4: hydra_body<4>(X, W, I, out, Xs, Smx, j, b, chunk); break;
    case 5: hydra_body<5>(X, W, I, out, Xs, Smx, j, b, chunk); break;
    case 6: hydra_body<6>(X, W, I, out, Xs, Smx, j, b, chunk); break;
    case 7: hydra_body<7>(X, W, I, out, Xs, Smx, j, b, chunk); break;
    case 8: hydra_body<8>(X, W, I, out, Xs, Smx, j, b, chunk); break;
    case 9: hydra_body<9>(X, W, I, out, Xs, Smx, j, b, chunk); break;
  }
}

__global__ void hydra_relu(float* __restrict__ out, int n) {
  int i = blockIdx.x * 256 + threadIdx.x;
  if (i < n) out[i] = fmaxf(out[i], 0.f);
}

extern "C" void kernel_launch(void* const* d_in, const int* in_sizes, int n_in,
                              void* d_out, int out_size, void* d_ws, size_t ws_size,
                              hipStream_t stream) {
  const float* X = (const float*)d_in[0];
  const float* W = (const float*)d_in[1];
  const int*   I = (const int*)d_in[2];
  float* out = (float*)d_out;

  (void)hipMemsetAsync(d_out, 0, (size_t)out_size * sizeof(float), stream);
  hydra_fused<<<GRID, 256, 0, stream>>>(X, W, I, out);
  hydra_relu<<<(out_size + 255) / 256, 256, 0, stream>>>(out, out_size);
}

// Round 5
// 452.587 us; speedup vs baseline: 2.4374x; 2.4374x over previous
//
#include <hip/hip_runtime.h>

// HydraBackbonePlus: 10 dilations x {X, diffX} x 32 groups, 9-tap grouped dilated
// conv (8 out-ch per group), per-position argmax/argmin over 8 channels,
// histogram-reduced to (32, 1280, 8) with relu.
//
// R15 = R14 resubmit (container infra failure, kernel never ran), hardened:
//  - no __builtin_amdgcn_alignbit (removed in some LLVM): use (lo>>16)|(hi<<16),
//    clang pattern-matches to v_alignbit_b32
//  - Oh[7] high lane = literal +0.0 (e[7]>>16), junk lane provably zero
//  - uint -> unsigned int
// Design vs R12 (421 us): f16 LDS tile.
//  - stage channels as cvt_pkrtz f16 pairs (b32 pair stores, half write ops)
//  - channel sum via h8_t += (v_pk_add_f16): 40 f32 adds -> 20 pk per 8 pos
//  - ldsum: 12 -> 6 ds_read_b128 per 8 pos (8 f16 = one b128)
//  - E pairs = raw dwords, O pairs = funnel shift, tap8 folded into 5th fdot2
//  - LDS 39424 -> 23744 B => 6 blocks/CU (was 4); launch_bounds(256,5) caps
//    allocator at ~102 regs (no spill), runtime occupancy LDS-limited at 6.

typedef __fp16 h2_t __attribute__((ext_vector_type(2)));
typedef __fp16 h8_t __attribute__((ext_vector_type(8)));

#define NB    32
#define CIN   12
#define SEQ   8192
#define NG    32
#define CPER  6
#define OUTCH 1280
#define XS_H  7776     // 12 * 648 = max over DI of CIN*CS (f16 units, DI=4)
#define GRID  10240    // 20 (di,j) * 32 b * 16 chunks

#define MAX3F(a, b, c) ({ float _r; asm("v_max3_f32 %0, %1, %2, %3" \
    : "=v"(_r) : "v"(a), "v"(b), "v"(c)); _r; })
#define MIN3F(a, b, c) ({ float _r; asm("v_min3_f32 %0, %1, %2, %3" \
    : "=v"(_r) : "v"(a), "v"(b), "v"(c)); _r; })

template <int DI>
__device__ __forceinline__ void hydra_body(
    const float* __restrict__ X, const float* __restrict__ W,
    const int* __restrict__ I, float* __restrict__ out,
    __fp16* Xs, float* Smx, int j, int b, int chunk) {

  constexpr int d   = 1 << DI;
  constexpr int R   = (d < 16) ? d : 16;       // residues per tile row-set
  constexpr int rb  = (DI < 4) ? DI : 4;       // log2(R)
  constexpr int Mm  = SEQ / d;                 // m-extent of a residue
  constexpr int TMc = 512 / R;
  constexpr int TM  = (TMc < Mm) ? TMc : Mm;   // m per tile (R12 geometry)
  constexpr int MC  = Mm / TM;
  constexpr int RC  = d / R;
  constexpr int NR  = (RC * MC) / 16;          // chunks per block: 1 (DI<9), 2 (DI=9)
  constexpr int SR  = TM + 8;                  // row stride (exact halo), mult of 8
  constexpr int CS  = R * SR + 8;              // channel stride (f16), mult of 8
                                               // -> every b128 read 16B-aligned
  constexpr int CL  = (R >= 8) ? TM : (TM * R / 8);  // m per thread per rep
  constexpr int REP = (R == 16) ? 2 : 1;

  const int L = SEQ - j;
  const int tid = threadIdx.x;
  const int g = tid >> 3, s = tid & 7;

  // weights: 8 out-ch x 9 taps -> 5 half2 per channel (tap8 paired with 0)
  h2_t Wp[8][5];
  {
    const float* wp = W + (size_t)((DI * 2 + j) * 256 + g * 8) * 9;
#pragma unroll
    for (int k = 0; k < 8; ++k) {
#pragma unroll
      for (int t = 0; t < 4; ++t)
        Wp[k][t] = __builtin_amdgcn_cvt_pkrtz(wp[k * 9 + 2 * t], wp[k * 9 + 2 * t + 1]);
      Wp[k][4] = __builtin_amdgcn_cvt_pkrtz(wp[k * 9 + 8], 0.f);
    }
  }
  const __fp16* base[CPER];
  {
    const int* ip = I + ((DI * 2 + j) * NG + g) * CPER;
#pragma unroll
    for (int i = 0; i < CPER; ++i) base[i] = Xs + ip[i] * CS;
  }

  // zero the per-thread cmx slots (covered by the staging __syncthreads)
#pragma unroll
  for (int k = 0; k < 8; ++k) Smx[k * 256 + tid] = 0.f;

  // cmn: 8 bins as packed u8 lanes of one u64 (counts <= 64/thread)
  unsigned long long cmnp = 0ull;

  for (int n = 0; n < NR; ++n) {
    const int cidx = chunk + 16 * n;
    const int rc = cidx & (RC - 1);
    const int mc = cidx / RC;
    const int r0 = rc * R;
    const int m0 = mc * TM;

    if (NR > 1 && n) __syncthreads();

    // ---- stage 12-channel tile into LDS as f16 pairs, zero-padded ----
    {
      const float* xb0 = X + (size_t)b * CIN * SEQ;
      if (j == 0) {
        for (int f = tid; f < R * SR / 2; f += 256) {
          int rr = f & (R - 1), mm = (f >> rb) << 1;
          int mp = m0 + mm - 4;
          int pos = r0 + rr + mp * d;
          bool ok0 = (mp >= 0) && (pos < L);
          bool ok1 = (mp >= -1) && (pos + d < L);
          int lo = rr * SR + mm;
          const float* xp = xb0 + pos;
#pragma unroll
          for (int ch = 0; ch < CIN; ++ch) {
            float v0 = ok0 ? xp[0] : 0.f;
            float v1 = ok1 ? xp[d] : 0.f;
            *reinterpret_cast<h2_t*>(&Xs[ch * CS + lo]) =
                __builtin_amdgcn_cvt_pkrtz(v0, v1);
            xp += SEQ;
          }
        }
      } else {
        for (int f = tid; f < R * SR / 2; f += 256) {
          int rr = f & (R - 1), mm = (f >> rb) << 1;
          int mp = m0 + mm - 4;
          int pos = r0 + rr + mp * d;
          bool ok0 = (mp >= 0) && (pos < L);
          bool ok1 = (mp >= -1) && (pos + d < L);
          int lo = rr * SR + mm;
          const float* xp = xb0 + pos;
#pragma unroll
          for (int ch = 0; ch < CIN; ++ch) {
            float v0 = ok0 ? (xp[1] - xp[0]) : 0.f;
            float v1 = ok1 ? (xp[d + 1] - xp[d]) : 0.f;
            *reinterpret_cast<h2_t*>(&Xs[ch * CS + lo]) =
                __builtin_amdgcn_cvt_pkrtz(v0, v1);
            xp += SEQ;
          }
        }
      }
    }
    __syncthreads();

    // ---- compute: sliding f16 window, fdot2 conv, mantissa-tag binning ----
#pragma unroll
    for (int rep = 0; rep < REP; ++rep) {
      int rr = (R == 16) ? (s + (rep << 3)) : (s & (R - 1));
      int mst = (R >= 8) ? 0 : ((s >> rb) * CL);
      int rowoff = rr * SR + mst;

      auto ldsum = [&](int idx) {
        h8_t r = *reinterpret_cast<const h8_t*>(base[0] + idx);
#pragma unroll
        for (int i = 1; i < CPER; ++i)
          r += *reinterpret_cast<const h8_t*>(base[i] + idx);
        return r;
      };

      h8_t w0 = ldsum(rowoff);                 // x0..x7 (f16)
#pragma unroll 1
      for (int st = 0; st < CL; st += 8) {
        h8_t w1 = ldsum(rowoff + st + 8);      // x8..x15 (f16)
        uint4 u0 = __builtin_bit_cast(uint4, w0);
        uint4 u1 = __builtin_bit_cast(uint4, w1);
        unsigned int e[8] = {u0.x, u0.y, u0.z, u0.w, u1.x, u1.y, u1.z, u1.w};
        // E pairs = raw dwords; O pairs = funnel shift (-> v_alignbit);
        // Oh[7] high lane = +0.0 (its weight is 0 anyway)
        h2_t Eh[8], Oh[8];
#pragma unroll
        for (int i = 0; i < 8; ++i) Eh[i] = __builtin_bit_cast(h2_t, e[i]);
#pragma unroll
        for (int i = 0; i < 7; ++i)
          Oh[i] = __builtin_bit_cast(h2_t, (e[i] >> 16) | (e[i + 1] << 16));
        Oh[7] = __builtin_bit_cast(h2_t, e[7] >> 16);
#pragma unroll
        for (int p = 0; p < 8; ++p) {
          const h2_t* P = (p & 1) ? (Oh + (p >> 1)) : (Eh + (p >> 1));
          // conv (5 fdot2, tap8 in the (w8,0) pair) + mantissa-tag binning
          float zp[8];
#pragma unroll
          for (int k = 0; k < 8; ++k) {
            float acc = __builtin_amdgcn_fdot2(Wp[k][4], P[4], 0.f, false);
            acc = __builtin_amdgcn_fdot2(Wp[k][3], P[3], acc, false);
            acc = __builtin_amdgcn_fdot2(Wp[k][2], P[2], acc, false);
            acc = __builtin_amdgcn_fdot2(Wp[k][1], P[1], acc, false);
            acc = __builtin_amdgcn_fdot2(Wp[k][0], P[0], acc, false);
            zp[k] = __uint_as_float((__float_as_uint(acc) & 0xFFFFFFF8u) | (unsigned)k);
          }
          // max/min trees via v_max3/v_min3: 4+4 ops
          float t1 = MAX3F(zp[0], zp[1], zp[2]);
          float t2 = MAX3F(zp[3], zp[4], zp[5]);
          float t3 = MAX3F(zp[6], zp[7], t1);
          float mxp = fmaxf(t2, t3);
          float u1v = MIN3F(zp[0], zp[1], zp[2]);
          float u2v = MIN3F(zp[3], zp[4], zp[5]);
          float u3v = MIN3F(zp[6], zp[7], u1v);
          float mnp = fminf(u2v, u3v);
          // cmx: contention-free per-thread LDS slot, plain pipelined RMW
          unsigned mxb = __float_as_uint(mxp);
          Smx[((mxb & 7u) << 8) + tid] += mxp;   // tagged val: <=8 ulp bias
          // cmn: packed-byte histogram in a u64 register
          unsigned mnb = __float_as_uint(mnp);
          cmnp += 1ull << ((mnb & 7u) << 3);
        }
        w0 = w1;
      }
    }
  }

  __syncthreads();

  // ---- flush ----
  {
    int cbase = (DI * 2 + j) * 64;
    // cmx: thread (g,s) sums bin=s over its 8 member threads
    float sum = 0.f;
#pragma unroll
    for (int s2 = 0; s2 < 8; ++s2) sum += Smx[(s << 8) + (g << 3) + s2];
    atomicAdd(out + ((size_t)b * OUTCH + cbase + g) * 8 + s, sum);

    // cmn: unpack bytes, butterfly over the 8 s-lanes, lane s commits bin s
    int cnts[8];
#pragma unroll
    for (int k = 0; k < 8; ++k) cnts[k] = (int)((cmnp >> (k * 8)) & 0xFFull);
#pragma unroll
    for (int k = 0; k < 8; ++k) {
#pragma unroll
      for (int off = 1; off < 8; off <<= 1)
        cnts[k] += __shfl_xor(cnts[k], off);
    }
    int vn = cnts[0];
#pragma unroll
    for (int k = 1; k < 8; ++k) vn = (s == k) ? cnts[k] : vn;
    atomicAdd(out + ((size_t)b * OUTCH + cbase + 32 + g) * 8 + s, (float)vn);
  }
}

__global__ __launch_bounds__(256, 5) void hydra_fused(
    const float* __restrict__ X, const float* __restrict__ W,
    const int* __restrict__ I, float* __restrict__ out) {
  __shared__ __fp16 Xs[XS_H];
  __shared__ float Smx[2048];   // 8 bins x 256 threads
  int u = blockIdx.x;
  int dj = u % 20;            // consecutive blocks interleave (di,j)
  int rest = u / 20;
  int b = rest & 31;
  int chunk = rest >> 5;
  int j = dj & 1;
  switch (dj >> 1) {
    case 0: hydra_body<0>(X, W, I, out, Xs, Smx, j, b, chunk); break;
    case 1: hydra_body<1>(X, W, I, out, Xs, Smx, j, b, chunk); break;
    case 2: hydra_body<2>(X, W, I, out, Xs, Smx, j, b, chunk); break;
    case 3: hydra_body<3>(X, W, I, out, Xs, Smx, j, b, chunk); break;
    case 4: hydra_body<4>(X, W, I, out, Xs, Smx, j, b, chunk); break;
    case 5: hydra_body<5>(X, W, I, out, Xs, Smx, j, b, chunk); break;
    case 6: hydra_body<6>(X, W, I, out, Xs, Smx, j, b, chunk); break;
    case 7: hydra_body<7>(X, W, I, out, Xs, Smx, j, b, chunk); break;
    case 8: hydra_body<8>(X, W, I, out, Xs, Smx, j, b, chunk); break;
    case 9: hydra_body<9>(X, W, I, out, Xs, Smx, j, b, chunk); break;
  }
}

__global__ void hydra_relu(float* __restrict__ out, int n) {
  int i = blockIdx.x * 256 + threadIdx.x;
  if (i < n) out[i] = fmaxf(out[i], 0.f);
}

extern "C" void kernel_launch(void* const* d_in, const int* in_sizes, int n_in,
                              void* d_out, int out_size, void* d_ws, size_t ws_size,
                              hipStream_t stream) {
  const float* X = (const float*)d_in[0];
  const float* W = (const float*)d_in[1];
  const int*   I = (const int*)d_in[2];
  float* out = (float*)d_out;

  (void)hipMemsetAsync(d_out, 0, (size_t)out_size * sizeof(float), stream);
  hydra_fused<<<GRID, 256, 0, stream>>>(X, W, I, out);
  hydra_relu<<<(out_size + 255) / 256, 256, 0, stream>>>(out, out_size);
}